// Round 1
// baseline (412.415 us; speedup 1.0000x reference)
//
#include <hip/hip_runtime.h>
#include <hip/hip_bf16.h>

typedef unsigned short u16;
typedef unsigned int u32;
typedef __bf16 bf16x8 __attribute__((ext_vector_type(8)));
typedef float f32x4 __attribute__((ext_vector_type(4)));
typedef u16 u16x4 __attribute__((ext_vector_type(4)));
typedef u16 u16x8 __attribute__((ext_vector_type(8)));

#define D_IN 4096
#define D_OUT 4096
#define M_TOT 8192
#define RANK_ 16

#define BM 128
#define BN 128
#define BK 32

__device__ __forceinline__ u16 f2bf(float f) {
    union { float f; u32 u; } v; v.f = f;
    u32 u = v.u;
    u32 r = (u + 0x7FFFu + ((u >> 16) & 1u)) >> 16;  // round-to-nearest-even
    return (u16)r;
}

// W_eff[o,i] = q[o,i]*scale[o] + min[o] + 2*sum_r B[o,r]*A[r,i]  -> bf16
__global__ void dequant_fold_kernel(const int* __restrict__ q,
                                    const float* __restrict__ wmin,
                                    const float* __restrict__ wscale,
                                    const float* __restrict__ A,
                                    const float* __restrict__ Bm,
                                    u16* __restrict__ Wb) {
    const int K = D_IN;
    int o = blockIdx.x;
    float sc = wscale[o];
    float mn = wmin[o];
    __shared__ float Brow[RANK_];
    if (threadIdx.x < RANK_) Brow[threadIdx.x] = 2.0f * Bm[o * RANK_ + threadIdx.x];
    __syncthreads();
    const int4* q4 = (const int4*)(q + (size_t)o * K);
    u16* op = Wb + (size_t)o * K;
    for (int i4 = threadIdx.x; i4 < K / 4; i4 += blockDim.x) {
        int4 qv = q4[i4];
        float v0 = (float)qv.x * sc + mn;
        float v1 = (float)qv.y * sc + mn;
        float v2 = (float)qv.z * sc + mn;
        float v3 = (float)qv.w * sc + mn;
        int i = i4 * 4;
        #pragma unroll
        for (int r = 0; r < RANK_; ++r) {
            float4 av = *(const float4*)(A + (size_t)r * K + i);
            float br = Brow[r];
            v0 += br * av.x; v1 += br * av.y; v2 += br * av.z; v3 += br * av.w;
        }
        u16x4 ov;
        ov.x = f2bf(v0); ov.y = f2bf(v1); ov.z = f2bf(v2); ov.w = f2bf(v3);
        *(u16x4*)(op + i) = ov;
    }
}

// fp32 -> bf16, 8 elems/thread, exact grid (no tail)
__global__ void xcast_kernel(const float* __restrict__ x, u16* __restrict__ xb) {
    size_t i = (size_t)blockIdx.x * blockDim.x + threadIdx.x;
    const float4* p = (const float4*)x + i * 2;
    float4 a = p[0];
    float4 b = p[1];
    u16x8 o;
    o[0] = f2bf(a.x); o[1] = f2bf(a.y); o[2] = f2bf(a.z); o[3] = f2bf(a.w);
    o[4] = f2bf(b.x); o[5] = f2bf(b.y); o[6] = f2bf(b.z); o[7] = f2bf(b.w);
    *(u16x8*)(xb + i * 8) = o;
}

// C[M,N] = Xb[M,K] * Wb[N,K]^T + bias ; bf16 in, fp32 out.
// m97 structure: 128x128 tile, BK=32, 4 waves (2x2), 4x4 16x16 frags/wave,
// global_load_lds width=16 staging, 2 barriers per K-step.
__global__ __launch_bounds__(256) void gemm_bt_kernel(const u16* __restrict__ Xb,
                                                      const u16* __restrict__ Wb,
                                                      const float* __restrict__ bias,
                                                      float* __restrict__ out) {
    const int K = D_IN, N = D_OUT;
    __shared__ __align__(16) u16 As[BM * BK];
    __shared__ __align__(16) u16 Bs[BN * BK];

    int nwg = gridDim.x;            // 2048, divisible by 8
    int bid = blockIdx.x;
    int cpx = nwg >> 3;
    int swz = (bid & 7) * cpx + (bid >> 3);   // XCD-aware swizzle (bijective: nwg%8==0)
    int tM = swz >> 5;              // 64 M-tiles
    int tN = swz & 31;              // 32 N-tiles

    int t = threadIdx.x;
    int lane = t & 63;
    int w = t >> 6;
    int wr = w >> 1;
    int wc = w & 1;

    f32x4 acc[4][4];
    #pragma unroll
    for (int i = 0; i < 4; ++i)
        #pragma unroll
        for (int j = 0; j < 4; ++j)
            acc[i][j] = (f32x4){0.f, 0.f, 0.f, 0.f};

    const u16* Ag = Xb + (size_t)tM * BM * K;
    const u16* Bg = Wb + (size_t)tN * BN * K;

    int lrow = lane & 15;
    int koff = (lane >> 4) << 3;

    for (int k0 = 0; k0 < K; k0 += BK) {
        // stage A-tile [128][32] and B-tile [128][32] via async global->LDS, 16B/lane
        #pragma unroll
        for (int j = 0; j < 2; ++j) {
            int c = t + j * 256;          // chunk 0..511
            int row = c >> 2;
            int col = (c & 3) << 3;
            __builtin_amdgcn_global_load_lds(
                (__attribute__((address_space(1))) u32*)(Ag + (size_t)row * K + k0 + col),
                (__attribute__((address_space(3))) u32*)(&As[c * 8]),
                16, 0, 0);
            __builtin_amdgcn_global_load_lds(
                (__attribute__((address_space(1))) u32*)(Bg + (size_t)row * K + k0 + col),
                (__attribute__((address_space(3))) u32*)(&Bs[c * 8]),
                16, 0, 0);
        }
        __syncthreads();   // drains vmcnt -> tiles ready

        bf16x8 a[4], b[4];
        #pragma unroll
        for (int f = 0; f < 4; ++f)
            a[f] = *(const bf16x8*)(&As[(wr * 64 + f * 16 + lrow) * BK + koff]);
        #pragma unroll
        for (int f = 0; f < 4; ++f)
            b[f] = *(const bf16x8*)(&Bs[(wc * 64 + f * 16 + lrow) * BK + koff]);
        #pragma unroll
        for (int fi = 0; fi < 4; ++fi)
            #pragma unroll
            for (int fj = 0; fj < 4; ++fj)
                acc[fi][fj] = __builtin_amdgcn_mfma_f32_16x16x32_bf16(
                    a[fi], b[fj], acc[fi][fj], 0, 0, 0);
        __syncthreads();   // protect LDS before next stage
    }

    // epilogue: C/D layout col=lane&15, row=(lane>>4)*4+reg  [m89-verified]
    int crow0 = (lane >> 4) << 2;
    int ccol = lane & 15;
    #pragma unroll
    for (int fi = 0; fi < 4; ++fi) {
        #pragma unroll
        for (int fj = 0; fj < 4; ++fj) {
            int n = tN * BN + wc * 64 + fj * 16 + ccol;
            float bs = bias[n];
            #pragma unroll
            for (int r = 0; r < 4; ++r) {
                int m = tM * BM + wr * 64 + fi * 16 + crow0 + r;
                out[(size_t)m * N + n] = acc[fi][fj][r] + bs;
            }
        }
    }
}

extern "C" void kernel_launch(void* const* d_in, const int* in_sizes, int n_in,
                              void* d_out, int out_size, void* d_ws, size_t ws_size,
                              hipStream_t stream) {
    (void)in_sizes; (void)n_in; (void)out_size; (void)ws_size;
    const float* x      = (const float*)d_in[0];
    const int*   qw     = (const int*)d_in[1];
    const float* wmin   = (const float*)d_in[2];
    const float* wscale = (const float*)d_in[3];
    const float* bias   = (const float*)d_in[4];
    const float* A      = (const float*)d_in[5];
    const float* Bm     = (const float*)d_in[6];
    float* out = (float*)d_out;

    u16* Wb = (u16*)d_ws;                         // 4096*4096*2 = 33.5 MB
    u16* Xb = Wb + (size_t)D_OUT * D_IN;          // 8192*4096*2 = 67.1 MB

    dequant_fold_kernel<<<D_OUT, 256, 0, stream>>>(qw, wmin, wscale, A, Bm, Wb);
    xcast_kernel<<<(M_TOT * D_IN) / (256 * 8), 256, 0, stream>>>(x, Xb);
    gemm_bt_kernel<<<(M_TOT / BM) * (D_OUT / BN), 256, 0, stream>>>(Xb, Wb, bias, out);
}